// Round 1
// baseline (447.889 us; speedup 1.0000x reference)
//
#include <hip/hip_runtime.h>

// Problem constants (from reference setup_inputs)
constexpr int B = 2, C = 16, D = 80, H = 96, W = 96;
constexpr int S  = D * H * W;        // 737280 spatial per batch
constexpr int N  = B * C * S;        // 23592960 elems per tensor
// Padded pooled layout: halo of 3 on d/h; w gets 4 left (alignment) + 12 right
constexpr int DP = D + 6;            // 86
constexpr int HP = H + 6;            // 102
constexpr int WP = 112;              // 4 + 96 + 12, multiple of 4 for float4 rows
constexpr int PP = DP * HP * WP;     // 982464 per channel per batch

// Workspace float offsets (all multiples of 4 -> float4 aligned)
constexpr int OFF_FMAX = 0;
constexpr int OFF_FAVG = B * PP;             // 1964928
constexpr int OFF_MMAX = 2 * B * PP;
constexpr int OFF_MAVG = 3 * B * PP;
constexpr int OFF_GF   = 4 * B * PP;         // 7859712
constexpr int OFF_GM   = OFF_GF + B * S;     // 9334272
// Total ws need: (OFF_GM + B*S)*4 bytes = 43,235,328 bytes

__device__ __forceinline__ float sigmoidf_(float x) {
    return 1.0f / (1.0f + __expf(-x));
}

// ---------------------------------------------------------------------------
// Kernel 1: channel max/mean pool of fix and move, written into zero-padded
// planar layout [ch][b][dp][hp][wp]. Halos already zeroed by memset.
// One thread per (b,d,h,w4) float4 group. Grid is exact: B*D*H*(W/4)/256.
// ---------------------------------------------------------------------------
__global__ __launch_bounds__(256) void pool_pad_kernel(
    const float* __restrict__ fix, const float* __restrict__ mov,
    float* __restrict__ ws)
{
    int i  = blockIdx.x * 256 + threadIdx.x;        // over B*D*H*(W/4)
    int w4 = i % (W / 4);
    int t  = i / (W / 4);
    int h  = t % H;  t /= H;
    int d  = t % D;
    int b  = t / D;

    const float4* f4 = (const float4*)fix;
    const float4* m4 = (const float4*)mov;
    int base = (b * C * S + (d * H + h) * W) / 4 + w4;   // channel 0 slot
    constexpr int cs = S / 4;                            // channel stride in float4

    float4 v = f4[base];
    float4 fmx = v, fsm = v;
    #pragma unroll
    for (int c = 1; c < C; c++) {
        v = f4[base + c * cs];
        fmx.x = fmaxf(fmx.x, v.x); fmx.y = fmaxf(fmx.y, v.y);
        fmx.z = fmaxf(fmx.z, v.z); fmx.w = fmaxf(fmx.w, v.w);
        fsm.x += v.x; fsm.y += v.y; fsm.z += v.z; fsm.w += v.w;
    }
    v = m4[base];
    float4 mmx = v, msm = v;
    #pragma unroll
    for (int c = 1; c < C; c++) {
        v = m4[base + c * cs];
        mmx.x = fmaxf(mmx.x, v.x); mmx.y = fmaxf(mmx.y, v.y);
        mmx.z = fmaxf(mmx.z, v.z); mmx.w = fmaxf(mmx.w, v.w);
        msm.x += v.x; msm.y += v.y; msm.z += v.z; msm.w += v.w;
    }
    constexpr float inv = 1.0f / C;
    float4 fav = make_float4(fsm.x * inv, fsm.y * inv, fsm.z * inv, fsm.w * inv);
    float4 mav = make_float4(msm.x * inv, msm.y * inv, msm.z * inv, msm.w * inv);

    // padded float4 index: origin shift (+3,+3,+4)
    int pi = b * (PP / 4) + (d + 3) * (HP * WP / 4) + (h + 3) * (WP / 4) + (w4 + 1);
    float4* ws4 = (float4*)ws;
    ws4[OFF_FMAX / 4 + pi] = fmx;
    ws4[OFF_FAVG / 4 + pi] = fav;
    ws4[OFF_MMAX / 4 + pi] = mmx;
    ws4[OFF_MAVG / 4 + pi] = mav;
}

// ---------------------------------------------------------------------------
// Kernel 2: 7x7x7 conv over the 2 pooled channels + sigmoid -> gate arrays.
// Block (8,8,4): tx = w-tile (4 outputs), ty = h-tile (4 outputs), tz = d.
// Each thread: 4x4 (h,w) register tile at one d. Per (c,kd): load 10 padded
// rows of 3 float4 each, 784 FMAs. Weights staged in LDS (broadcast reads).
// Grid (3,3,80): z = tensor*40 + b*20 + dblk.
// ---------------------------------------------------------------------------
__global__ __launch_bounds__(256) void conv_gate_kernel(
    const float* __restrict__ ws_in,
    const float* __restrict__ w_f2m, const float* __restrict__ w_m2f,
    float* __restrict__ ws_out)
{
    __shared__ float wsm[2 * 343];
    int tid = threadIdx.x + threadIdx.y * 8 + threadIdx.z * 64;

    int z      = blockIdx.z;
    int tensor = z / (B * (D / 4));      // 0 = fix gate, 1 = move gate
    int zz     = z % (B * (D / 4));
    int b      = zz / (D / 4);
    int dblk   = zz % (D / 4);

    const float* wsrc = tensor ? w_m2f : w_f2m;
    for (int j = tid; j < 686; j += 256) wsm[j] = wsrc[j];
    __syncthreads();

    const float* pmax = ws_in + (tensor ? OFF_MMAX : OFF_FMAX) + b * PP;
    const float* pavg = ws_in + (tensor ? OFF_MAVG : OFF_FAVG) + b * PP;
    float*       gate = ws_out + (tensor ? OFF_GM : OFF_GF) + b * S;

    int d  = dblk * 4 + threadIdx.z;
    int hb = blockIdx.y * 32 + threadIdx.y * 4;
    int wb = blockIdx.x * 32 + threadIdx.x * 4;

    float acc[4][4];
    #pragma unroll
    for (int oh = 0; oh < 4; oh++)
        #pragma unroll
        for (int ow = 0; ow < 4; ow++) acc[oh][ow] = 0.0f;

    #pragma unroll 1
    for (int c = 0; c < 2; c++) {
        const float* src = c ? pavg : pmax;
        #pragma unroll 1
        for (int kd = 0; kd < 7; kd++) {
            const float* plane = src + (d + kd) * (HP * WP);
            float wt[49];
            #pragma unroll
            for (int j = 0; j < 49; j++) wt[j] = wsm[(c * 7 + kd) * 49 + j];

            #pragma unroll
            for (int r = 0; r < 10; r++) {
                const float4* rp = (const float4*)(plane + (hb + r) * WP + wb);
                float4 a0 = rp[0], a1 = rp[1], a2 = rp[2];
                float row[12];
                row[0] = a0.x; row[1]  = a0.y; row[2]  = a0.z; row[3]  = a0.w;
                row[4] = a1.x; row[5]  = a1.y; row[6]  = a1.z; row[7]  = a1.w;
                row[8] = a2.x; row[9]  = a2.y; row[10] = a2.z; row[11] = a2.w;
                // padded row hb+r serves output rows oh with kh = r-oh in [0,7)
                #pragma unroll
                for (int oh = 0; oh < 4; oh++) {
                    int kh = r - oh;
                    if (kh >= 0 && kh < 7) {        // compile-time after unroll
                        #pragma unroll
                        for (int kw = 0; kw < 7; kw++) {
                            float wv = wt[kh * 7 + kw];
                            #pragma unroll
                            for (int ow = 0; ow < 4; ow++)
                                acc[oh][ow] = fmaf(row[ow + kw + 1], wv, acc[oh][ow]);
                        }
                    }
                }
            }
        }
    }

    #pragma unroll
    for (int oh = 0; oh < 4; oh++) {
        float4 o;
        o.x = sigmoidf_(acc[oh][0]);
        o.y = sigmoidf_(acc[oh][1]);
        o.z = sigmoidf_(acc[oh][2]);
        o.w = sigmoidf_(acc[oh][3]);
        *(float4*)(gate + (d * H + hb + oh) * W + wb) = o;
    }
}

// ---------------------------------------------------------------------------
// Kernel 3: elementwise cross-apply.
// fix_out = move*g_fix + fix ; move_out = fix*g_move + move.
// One thread per float4 of one tensor; writes both outputs.
// ---------------------------------------------------------------------------
__global__ __launch_bounds__(256) void apply_kernel(
    const float* __restrict__ fix, const float* __restrict__ mov,
    const float* __restrict__ ws, float* __restrict__ out)
{
    int i  = blockIdx.x * 256 + threadIdx.x;   // over N/4
    int w4 = i % (W / 4);
    int t  = i / (W / 4);
    int h  = t % H;  t /= H;
    int d  = t % D;  t /= D;
    int b  = t / C;                            // t = b*C + c

    const float4* f4  = (const float4*)fix;
    const float4* m4  = (const float4*)mov;
    const float4* gf4 = (const float4*)(ws + OFF_GF);
    const float4* gm4 = (const float4*)(ws + OFF_GM);
    float4*       o4  = (float4*)out;

    int sp = ((b * D + d) * H + h) * (W / 4) + w4;
    float4 f = f4[i], m = m4[i], gf = gf4[sp], gm = gm4[sp];

    float4 of, om;
    of.x = fmaf(m.x, gf.x, f.x); of.y = fmaf(m.y, gf.y, f.y);
    of.z = fmaf(m.z, gf.z, f.z); of.w = fmaf(m.w, gf.w, f.w);
    om.x = fmaf(f.x, gm.x, m.x); om.y = fmaf(f.y, gm.y, m.y);
    om.z = fmaf(f.z, gm.z, m.z); om.w = fmaf(f.w, gm.w, m.w);

    o4[i]         = of;
    o4[i + N / 4] = om;
}

extern "C" void kernel_launch(void* const* d_in, const int* in_sizes, int n_in,
                              void* d_out, int out_size, void* d_ws, size_t ws_size,
                              hipStream_t stream)
{
    const float* fix = (const float*)d_in[0];
    const float* mov = (const float*)d_in[1];
    const float* wf  = (const float*)d_in[2];   // w_f2m: gate from fix
    const float* wm  = (const float*)d_in[3];   // w_m2f: gate from move
    float* ws  = (float*)d_ws;
    float* out = (float*)d_out;

    // Zero the padded pooled arrays (halo must be 0 every call; ws is poisoned)
    hipMemsetAsync(d_ws, 0, (size_t)(4 * B * PP) * sizeof(float), stream);

    pool_pad_kernel<<<B * D * H * (W / 4) / 256, 256, 0, stream>>>(fix, mov, ws);

    dim3 cb(8, 8, 4), cg(3, 3, 2 * B * (D / 4));
    conv_gate_kernel<<<cg, cb, 0, stream>>>(ws, wf, wm, ws);

    apply_kernel<<<(N / 4) / 256, 256, 0, stream>>>(fix, mov, ws, out);
}